// Round 3
// baseline (156.388 us; speedup 1.0000x reference)
//
#include <hip/hip_runtime.h>
#include <math.h>

#define LTOK 4096
#define EDIM 512
#define SDIM 1024
#define HDIM 150
#define SEG 160            // padded segment width (cols) and P-row stride
#define MAXN 10
#define TOTAL_ROWS 40915   // sum_{n=1..10} (L - n + 1)
#define KA 1536            // padded K: 1024 states + 512 embeds
#define NKT 48             // k-tiles of 32
#define K2 160             // padded K and N for 150x150 layers
#define NCG 42             // packed-W col groups: P1(0-9)|P2(10-19)|PE(20-29)|pad(30-31)|attn(32-41)

typedef _Float16 hfrag __attribute__((ext_vector_type(8)));  // 8 fp16, 4 VGPRs
typedef float ffrag __attribute__((ext_vector_type(4)));     // MFMA C/D

// Packed-fragment layouts (fp16):
//   Wpk [(cg*48 + kt)*64 + lane][8]  : W[col=cg*16+l16][k=kt*32+quad*8+j]
//   W2pk/A2pk [(ct*5+ks)*64 + lane][8]
// A-fragments are built on the fly inside k_proj from states/embeds fp32
// (identical (_Float16) cast as the old prep -> bit-identical).
// Column map (col = cg*16 + l16):
//   [0,160)  P1  (cj=col,     k<1024,  sW1 rows 0..1023)
//   [160,320) P2 (cj=col-160, k<1024,  sW1 rows 1024..2047)
//   [320,480) PE (cj=col-320, k>=1024, sW1 rows 2048..2559)
//   [480,512) zero pad
//   [512,672) attn (cj=col-512, k<1024, aW1)

#define ITEMS_W   (NCG * NKT * 64)    // 129024
#define ITEMS_W2  (K2 * (K2 / 8))     // 3200 (sW2)
#define ITEMS_A2  (K2 * (K2 / 8))     // 3200 (aW2)
#define ITEMS_PREP (ITEMS_W + ITEMS_W2 + ITEMS_A2)   // 135424 = 529*256

// ---------------------------------------------------------------------------
// prep: weights only (fp32 -> fp16 + MFMA-fragment packing). ~1 us.
// ---------------------------------------------------------------------------
__global__ __launch_bounds__(256) void prep_kernel(
    const float* __restrict__ aW1, const float* __restrict__ aW2,
    const float* __restrict__ sW1, const float* __restrict__ sW2,
    _Float16* __restrict__ Wpk, _Float16* __restrict__ W2pk,
    _Float16* __restrict__ A2pk)
{
    int it = blockIdx.x * 256 + threadIdx.x;
    if (it < ITEMS_W) {
        const int rem = it % (NKT * 64);
        const int cgi = it / (NKT * 64), kt = rem >> 6, lane = rem & 63;
        const int col = cgi * 16 + (lane & 15);
        const int k0 = kt * 32 + (lane >> 4) * 8;
        _Float16 o[8];
        for (int j = 0; j < 8; ++j) {
            const int k = k0 + j;
            float wv = 0.f;
            if (col < 160) {
                if (col < HDIM && k < SDIM) wv = sW1[(size_t)k * HDIM + col];
            } else if (col < 320) {
                const int cj = col - 160;
                if (cj < HDIM && k < SDIM) wv = sW1[(size_t)(SDIM + k) * HDIM + cj];
            } else if (col < 480) {
                const int cj = col - 320;
                if (cj < HDIM && k >= SDIM) wv = sW1[(size_t)(SDIM + k) * HDIM + cj]; // rows 2048+(k-1024)
            } else if (col >= 512) {
                const int cj = col - 512;
                if (cj < HDIM && k < SDIM) wv = aW1[(size_t)k * HDIM + cj];
            }
            o[j] = (_Float16)wv;
        }
        *(uint4*)(Wpk + ((size_t)((size_t)cgi * NKT + kt) * 64 + lane) * 8) = *(uint4*)o;
        return;
    }
    it -= ITEMS_W;
    if (it < ITEMS_W2 + ITEMS_A2) {
        const bool is_a = (it >= ITEMS_W2);
        const int li = is_a ? (it - ITEMS_W2) : it;
        const float* src = is_a ? aW2 : sW2;
        _Float16* dst = is_a ? A2pk : W2pk;
        const int tk = li >> 6, lane = li & 63;          // tk = ct*5+ks (0..49)
        const int col = (tk / 5) * 16 + (lane & 15);
        const int k0 = (tk % 5) * 32 + (lane >> 4) * 8;
        _Float16 o[8];
        for (int j = 0; j < 8; ++j) {
            const int k = k0 + j;
            float wv = (col < HDIM && k < HDIM) ? src[(size_t)k * HDIM + col] : 0.f;
            o[j] = (_Float16)wv;
        }
        *(uint4*)(dst + ((size_t)tk * 64 + lane) * 8) = *(uint4*)o;
    }
}

// ---------------------------------------------------------------------------
// k_proj: bid%9==0 -> attention-scorer block (heavy, 64 tokens, idx bid/9);
// else main projection tile. A-fragments are converted from fp32 states/
// embeds on the fly (no Apk round-trip through HBM). Main tiles use the
// double-buffered LDS staging shared by all 4 waves. K-range pruning:
// bN 0..4 (P1/P2) kt [0,32); bN 5..7 (PE) kt [32,48).
// ---------------------------------------------------------------------------
__global__ __launch_bounds__(256) void k_proj(
    const float* __restrict__ states, const float* __restrict__ embeds,
    const _Float16* __restrict__ Wpk, const _Float16* __restrict__ A2pk,
    const float* __restrict__ ab1, const float* __restrict__ ab2,
    const float* __restrict__ aW3, const float* __restrict__ ab3,
    _Float16* __restrict__ P1h, _Float16* __restrict__ P2h,
    _Float16* __restrict__ PEh, float* __restrict__ attns)
{
    const int bid = blockIdx.x;
    const int tid = threadIdx.x;
    const int w = tid >> 6, lane = tid & 63;
    const int quad = lane >> 4, l16 = lane & 15;

    // 20 KB shared pool: attn path uses all of it as ah1[64*SEG];
    // main path carves As[2] (2x4KB) + Bs[2] (2x4KB) staging buffers.
    __shared__ __align__(16) _Float16 smem[64 * SEG];

    if (bid % 9 == 0) {
        // ---------------- attention scorer, 64 tokens ----------------
        _Float16* ah1 = smem;
        const int tok0 = (bid / 9) * 64;

        ffrag acc[10];
#pragma unroll
        for (int c = 0; c < 10; ++c) acc[c] = (ffrag){0.f, 0.f, 0.f, 0.f};

        // A-fragment source: row = tok0 + w*16 + l16, k = kt*32 + quad*8 + j
        const float* ap = states + (size_t)(tok0 + w * 16 + l16) * SDIM + quad * 8;
#pragma unroll 2
        for (int kt = 0; kt < 32; ++kt) {              // attn weights: k<1024
            const float4 v0 = *(const float4*)(ap + kt * 32);
            const float4 v1 = *(const float4*)(ap + kt * 32 + 4);
            hfrag a;
            a[0] = (_Float16)v0.x; a[1] = (_Float16)v0.y;
            a[2] = (_Float16)v0.z; a[3] = (_Float16)v0.w;
            a[4] = (_Float16)v1.x; a[5] = (_Float16)v1.y;
            a[6] = (_Float16)v1.z; a[7] = (_Float16)v1.w;
#pragma unroll
            for (int c = 0; c < 10; ++c) {
                const hfrag b = *(const hfrag*)(
                    Wpk + (((size_t)(32 + c) * NKT + kt) * 64 + lane) * 8);
                acc[c] = __builtin_amdgcn_mfma_f32_16x16x32_f16(a, b, acc[c], 0, 0, 0);
            }
        }
        // layer1 epilogue -> LDS (relu + bias)
#pragma unroll
        for (int c = 0; c < 10; ++c) {
            const int col = c * 16 + l16;
            const float b1 = (col < HDIM) ? ab1[col] : 0.f;
#pragma unroll
            for (int r = 0; r < 4; ++r) {
                const int row = w * 16 + quad * 4 + r;
                ah1[row * SEG + col] = (_Float16)fmaxf(acc[c][r] + b1, 0.f);
            }
        }
        __syncthreads();

        // layers 2+3: wave w -> its 16 tokens
        hfrag af[5];
#pragma unroll
        for (int ks = 0; ks < 5; ++ks)
            af[ks] = *(const hfrag*)&ah1[(w * 16 + l16) * SEG + ks * 32 + quad * 8];

        float part[4] = {0.f, 0.f, 0.f, 0.f};
        for (int ct = 0; ct < 10; ++ct) {
            ffrag a2 = (ffrag){0.f, 0.f, 0.f, 0.f};
#pragma unroll
            for (int ks = 0; ks < 5; ++ks) {
                const hfrag fb = *(const hfrag*)(
                    A2pk + ((size_t)(ct * 5 + ks) * 64 + lane) * 8);
                a2 = __builtin_amdgcn_mfma_f32_16x16x32_f16(af[ks], fb, a2, 0, 0, 0);
            }
            const int col = ct * 16 + l16;
            const float s2 = (col < HDIM) ? ab2[col] : 0.f;
            const float s3 = (col < HDIM) ? aW3[col] : 0.f;
#pragma unroll
            for (int r = 0; r < 4; ++r) part[r] += fmaxf(a2[r] + s2, 0.f) * s3;
        }
#pragma unroll
        for (int off = 1; off < 16; off <<= 1) {
#pragma unroll
            for (int r = 0; r < 4; ++r) part[r] += __shfl_xor(part[r], off, 64);
        }
        if (l16 == 0) {
            const float b3 = ab3[0];
#pragma unroll
            for (int r = 0; r < 4; ++r)
                attns[tok0 + w * 16 + quad * 4 + r] = part[r] + b3;
        }
        return;
    }

    // ---------------- main projection tiles (LDS double-buffered) ----------
    const int tile = bid - bid / 9 - 1;                // [0, 512)
    const int bM = tile & 63, bN = tile >> 6;          // bN in [0,8)
    const int wm = w & 1, wn = w >> 1;
    const int gbase0 = bM * 4;                         // block row-group base
    const int cgbase0 = bN * 4;                        // block col-group base
    const int cgbase = cgbase0 + wn * 2;
    const bool alive = (cgbase < 30);                  // pad col-groups: compute
                                                       // on zeros, skip writes
    const int kt0 = (bN >= 5) ? 32 : 0;                // PE segment: k>=1024 only
    const int kt1 = (bN >= 5) ? 48 : 32;               // P1/P2: k<1024 only

    // staging carve: As[buf] at smem + buf*2048, Bs[buf] at smem+4096+buf*2048
    _Float16* As = smem;
    _Float16* Bs = smem + 4096;

    // per-thread staging slot: grp = tid>>6 (0..3), ln = tid&63
    const int sgrp = tid >> 6, sln = tid & 63;
    const int srow = (gbase0 + sgrp) * 16 + (sln & 15);   // A source row
    const int skcol = (sln >> 4) * 8;                     // k offset within kt
    const float* aRowS = states + (size_t)srow * SDIM;
    const float* aRowE = embeds + (size_t)srow * EDIM;
    const _Float16* bSrc = Wpk + (((size_t)(cgbase0 + sgrp) * NKT) * 64 + sln) * 8;
    const int sOff = (sgrp * 64 + sln) * 8;            // LDS element offset

    ffrag acc[2][2];
#pragma unroll
    for (int t = 0; t < 2; ++t)
#pragma unroll
        for (int u = 0; u < 2; ++u) acc[t][u] = (ffrag){0.f, 0.f, 0.f, 0.f};

    // wave fragment read offsets within a buffer
    const int aOff0 = ((wm * 2 + 0) * 64 + lane) * 8;
    const int aOff1 = ((wm * 2 + 1) * 64 + lane) * 8;
    const int bOff0 = ((wn * 2 + 0) * 64 + lane) * 8;
    const int bOff1 = ((wn * 2 + 1) * 64 + lane) * 8;

    // A load helper (uniform branch per block: kt<32 -> states, else embeds)
#define A_LOAD(kt, d0, d1)                                                  \
    {                                                                       \
        const int k0_ = (kt) * 32 + skcol;                                  \
        const float* s_ = (k0_ < SDIM) ? (aRowS + k0_)                      \
                                       : (aRowE + (k0_ - SDIM));            \
        d0 = *(const float4*)s_;                                            \
        d1 = *(const float4*)(s_ + 4);                                      \
    }
#define A_STORE(buf_, d0, d1)                                               \
    {                                                                       \
        _Float16 o_[8] = {(_Float16)d0.x, (_Float16)d0.y, (_Float16)d0.z,   \
                          (_Float16)d0.w, (_Float16)d1.x, (_Float16)d1.y,   \
                          (_Float16)d1.z, (_Float16)d1.w};                  \
        *(uint4*)(As + (buf_) * 2048 + sOff) = *(uint4*)o_;                 \
    }

    // prologue: stage kt0 into buf 0; queue kt0+1 in regs
    {
        float4 p0, p1;
        A_LOAD(kt0, p0, p1);
        A_STORE(0, p0, p1);
        *(uint4*)(Bs + sOff) = *(const uint4*)(bSrc + (size_t)kt0 * 512);
    }
    float4 qa0, qa1; uint4 qb;
    if (kt0 + 1 < kt1) {
        A_LOAD(kt0 + 1, qa0, qa1);
        qb = *(const uint4*)(bSrc + (size_t)(kt0 + 1) * 512);
    }
    __syncthreads();

    int buf = 0;
    for (int kt = kt0; kt < kt1; ++kt) {
        float4 na0, na1; uint4 nb;
        const bool have2 = (kt + 2 < kt1);
        const bool have1 = (kt + 1 < kt1);
        if (have2) {                                   // depth-2 prefetch issue
            A_LOAD(kt + 2, na0, na1);
            nb = *(const uint4*)(bSrc + (size_t)(kt + 2) * 512);
        }
        if (have1) {                                   // write queued kt+1
            A_STORE(buf ^ 1, qa0, qa1);
            *(uint4*)(Bs + (buf ^ 1) * 2048 + sOff) = qb;
        }
        const _Float16* Ab = As + buf * 2048;
        const _Float16* Bb = Bs + buf * 2048;
        const hfrag a0 = *(const hfrag*)(Ab + aOff0);
        const hfrag a1 = *(const hfrag*)(Ab + aOff1);
        const hfrag b0 = *(const hfrag*)(Bb + bOff0);
        const hfrag b1 = *(const hfrag*)(Bb + bOff1);
        acc[0][0] = __builtin_amdgcn_mfma_f32_16x16x32_f16(a0, b0, acc[0][0], 0, 0, 0);
        acc[1][0] = __builtin_amdgcn_mfma_f32_16x16x32_f16(a1, b0, acc[1][0], 0, 0, 0);
        acc[0][1] = __builtin_amdgcn_mfma_f32_16x16x32_f16(a0, b1, acc[0][1], 0, 0, 0);
        acc[1][1] = __builtin_amdgcn_mfma_f32_16x16x32_f16(a1, b1, acc[1][1], 0, 0, 0);
        __syncthreads();
        qa0 = na0; qa1 = na1; qb = nb;
        buf ^= 1;
    }
#undef A_LOAD
#undef A_STORE

    if (alive) {
#pragma unroll
        for (int t = 0; t < 2; ++t)
#pragma unroll
            for (int u = 0; u < 2; ++u) {
                const int col = (cgbase + u) * 16 + l16;
#pragma unroll
                for (int r = 0; r < 4; ++r) {
                    const int row = (gbase0 + wm * 2 + t) * 16 + quad * 4 + r;
                    const _Float16 hv = (_Float16)acc[t][u][r];
                    if (col < 160)      P1h[(size_t)row * SEG + col] = hv;
                    else if (col < 320) P2h[(size_t)row * SEG + (col - 160)] = hv;
                    else if (col < 480) PEh[(size_t)row * SEG + (col - 320)] = hv;
                }
            }
    }
}

// ---------------------------------------------------------------------------
// span (n-paired, interleaved): pairI = bid % 5, mChunk = bid / 5. Handles
// n0=2*pairI+1 and n1=n0+1 for 32 m-values, sharing P1/PE loads. The 41
// unique PE rows (clamped) are staged once in LDS (13 KB) instead of being
// re-read ~10x from L2. PE loop fully unrolled to MAXN with zero weights
// past n (exact no-op fmaf).
// ---------------------------------------------------------------------------
__global__ __launch_bounds__(256) void span_kernel(
    const float* __restrict__ attns, const _Float16* __restrict__ P1h,
    const _Float16* __restrict__ P2h, const _Float16* __restrict__ PEh,
    const float* __restrict__ sb1, const _Float16* __restrict__ W2pk,
    const float* __restrict__ sb2, const float* __restrict__ sW3,
    const float* __restrict__ sb3, float* __restrict__ out)
{
    const int pairI = blockIdx.x % 5;         // 0..4 (interleaved heavy/light)
    const int mChunk = blockIdx.x / 5;        // 0..127
    const int n0 = 2 * pairI + 1, n1 = n0 + 1;
    const int Mn0 = LTOK - n0 + 1, Mn1 = Mn0 - 1;
    const int m0 = mChunk * 32;
    const int offn0 = (n0 - 1) * LTOK - ((n0 - 1) * (n0 - 2)) / 2;
    const int offn1 = offn0 + Mn0;

    const int tid = threadIdx.x;
    const int w = tid >> 6, lane = tid & 63, quad = lane >> 4, l16 = lane & 15;

    __shared__ __align__(16) _Float16 h1h[2][32 * K2];
    __shared__ __align__(16) _Float16 PEs[41 * SEG];   // staged PE rows (13 KB)
    __shared__ float wgt[2][32][MAXN];

    // stage PE rows m0..m0+40 (row-clamped) into LDS; row rr holds
    // PEh[min(m0+rr, L-1)] so phase-1 index (r+j) is exactly the clamped row.
    for (int t = tid; t < 41 * (SEG / 8); t += 256) {
        const int rr = t / (SEG / 8), cc = t % (SEG / 8);
        const int srcRow = min(m0 + rr, LTOK - 1);
        *(uint4*)&PEs[rr * SEG + cc * 8] =
            *(const uint4*)(PEh + (size_t)srcRow * SEG + cc * 8);
    }

    if (tid < 64) {
        const int q = tid >> 5, r = tid & 31;
        const int n = q ? n1 : n0;
        const int Mn = q ? Mn1 : Mn0;
        const int m = m0 + r;
        if (m < Mn) {
            float av[MAXN];
#pragma unroll
            for (int j = 0; j < MAXN; ++j)
                av[j] = attns[min(m + j, LTOK - 1)];   // parallel clamped loads
            float mx = -1e30f;
            for (int j = 0; j < n; ++j) mx = fmaxf(mx, av[j]);
            float tp[MAXN]; float s = 0.f;
            for (int j = 0; j < n; ++j) { tp[j] = expf(av[j] - mx); s += tp[j]; }
            const float inv = 1.f / s;
            for (int j = 0; j < MAXN; ++j) wgt[q][r][j] = (j < n) ? tp[j] * inv : 0.f;
        } else {
            for (int j = 0; j < MAXN; ++j) wgt[q][r][j] = 0.f;
        }
    }
    __syncthreads();

    // phase 1: 32 rows x 20 col-chunks (8 cols), BOTH n per item; full unroll
    for (int item = tid; item < 32 * (K2 / 8); item += 256) {
        const int r = item / (K2 / 8), cc = item % (K2 / 8);
        const int c0 = cc * 8;
        const int mm = m0 + r;                       // < 4096 always
        const hfrag p1  = *(const hfrag*)(P1h + (size_t)mm * SEG + c0);
        const hfrag p2a = *(const hfrag*)(P2h + (size_t)min(mm + n0 - 1, LTOK - 1) * SEG + c0);
        const hfrag p2b = *(const hfrag*)(P2h + (size_t)min(mm + n0, LTOK - 1) * SEG + c0);
        float b1v[8];
#pragma unroll
        for (int e = 0; e < 8; ++e)
            b1v[e] = (c0 + e < HDIM) ? sb1[c0 + e] : 0.f;
        float a0[8], a1[8];
#pragma unroll
        for (int e = 0; e < 8; ++e) {
            a0[e] = (float)p1[e] + (float)p2a[e] + b1v[e];
            a1[e] = (float)p1[e] + (float)p2b[e] + b1v[e];
        }
#pragma unroll
        for (int j = 0; j < MAXN; ++j) {             // weights 0 past n -> exact no-op
            const hfrag pe = *(const hfrag*)&PEs[(r + j) * SEG + c0];
            const float w0j = wgt[0][r][j];
            const float w1j = wgt[1][r][j];
#pragma unroll
            for (int e = 0; e < 8; ++e) {
                const float pv = (float)pe[e];
                a0[e] = fmaf(w0j, pv, a0[e]);
                a1[e] = fmaf(w1j, pv, a1[e]);
            }
        }
        _Float16 o0[8], o1[8];
#pragma unroll
        for (int e = 0; e < 8; ++e) {
            const bool live = (c0 + e < HDIM);
            o0[e] = live ? (_Float16)fmaxf(a0[e], 0.f) : (_Float16)0.f;
            o1[e] = live ? (_Float16)fmaxf(a1[e], 0.f) : (_Float16)0.f;
        }
        *(uint4*)&h1h[0][r * K2 + c0] = *(uint4*)o0;
        *(uint4*)&h1h[1][r * K2 + c0] = *(uint4*)o1;
    }
    __syncthreads();

    // phase 2: wave w -> side q = w>>1, row-group rg = w&1 (16 rows)
    const int q = w >> 1, rg = w & 1;
    const int Mq = q ? Mn1 : Mn0;
    const int offq = q ? offn1 : offn0;

    hfrag af[5];
#pragma unroll
    for (int ks = 0; ks < 5; ++ks)
        af[ks] = *(const hfrag*)&h1h[q][(rg * 16 + l16) * K2 + ks * 32 + quad * 8];

    float part[4] = {0.f, 0.f, 0.f, 0.f};
    for (int ct = 0; ct < 10; ++ct) {
        ffrag acc = (ffrag){0.f, 0.f, 0.f, 0.f};
#pragma unroll
        for (int ks = 0; ks < 5; ++ks) {
            const hfrag fb = *(const hfrag*)(
                W2pk + ((size_t)(ct * 5 + ks) * 64 + lane) * 8);
            acc = __builtin_amdgcn_mfma_f32_16x16x32_f16(af[ks], fb, acc, 0, 0, 0);
        }
        const int col = ct * 16 + l16;
        const float s2 = (col < HDIM) ? sb2[col] : 0.f;
        const float s3 = (col < HDIM) ? sW3[col] : 0.f;
#pragma unroll
        for (int r = 0; r < 4; ++r) part[r] += fmaxf(acc[r] + s2, 0.f) * s3;
    }

#pragma unroll
    for (int off = 1; off < 16; off <<= 1) {
#pragma unroll
        for (int r = 0; r < 4; ++r) part[r] += __shfl_xor(part[r], off, 64);
    }
    if (l16 == 0) {
        const float b3 = sb3[0];
#pragma unroll
        for (int r = 0; r < 4; ++r) {
            const int lr = rg * 16 + quad * 4 + r;   // 0..31
            if (m0 + lr < Mq) out[offq + m0 + lr] = part[r] + b3;
        }
    }
}

// ---------------------------------------------------------------------------
extern "C" void kernel_launch(void* const* d_in, const int* in_sizes, int n_in,
                              void* d_out, int out_size, void* d_ws, size_t ws_size,
                              hipStream_t stream) {
    const float* embeds = (const float*)d_in[0];
    const float* states = (const float*)d_in[1];
    const float* aW1 = (const float*)d_in[2];
    const float* ab1 = (const float*)d_in[3];
    const float* aW2 = (const float*)d_in[4];
    const float* ab2 = (const float*)d_in[5];
    const float* aW3 = (const float*)d_in[6];
    const float* ab3 = (const float*)d_in[7];
    const float* sW1 = (const float*)d_in[8];
    const float* sb1 = (const float*)d_in[9];
    const float* sW2 = (const float*)d_in[10];
    const float* sb2 = (const float*)d_in[11];
    const float* sW3 = (const float*)d_in[12];
    const float* sb3 = (const float*)d_in[13];
    float* out = (float*)d_out;

    // ws: fp32 attns | fp16 P1h | P2h | PEh (SEG rows) | Wpk | W2pk | A2pk
    float* attns = (float*)d_ws;
    _Float16* P1h  = (_Float16*)(attns + LTOK);
    _Float16* P2h  = P1h + (size_t)LTOK * SEG;
    _Float16* PEh  = P2h + (size_t)LTOK * SEG;
    _Float16* Wpk  = PEh + (size_t)LTOK * SEG;
    _Float16* W2pk = Wpk + (size_t)ITEMS_W * 8;
    _Float16* A2pk = W2pk + (size_t)ITEMS_W2 * 8;
    // total ~6 MB

    prep_kernel<<<ITEMS_PREP / 256, 256, 0, stream>>>(
        aW1, aW2, sW1, sW2, Wpk, W2pk, A2pk);
    k_proj<<<576, 256, 0, stream>>>(
        states, embeds, Wpk, A2pk, ab1, ab2, aW3, ab3, P1h, P2h, PEh, attns);
    span_kernel<<<640, 256, 0, stream>>>(
        attns, P1h, P2h, PEh, sb1, W2pk, sb2, sW3, sb3, out);
}

// Round 4
// 144.629 us; speedup vs baseline: 1.0813x; 1.0813x over previous
//
#include <hip/hip_runtime.h>
#include <math.h>

#define LTOK 4096
#define EDIM 512
#define SDIM 1024
#define HDIM 150
#define SEG 160            // padded segment width (cols) and P-row stride
#define MAXN 10
#define TOTAL_ROWS 40915   // sum_{n=1..10} (L - n + 1)
#define KA 1536            // padded K: 1024 states + 512 embeds
#define NKT 48             // k-tiles of 32
#define K2 160             // padded K and N for 150x150 layers
#define NCG 42             // packed-W col groups: P1(0-9)|P2(10-19)|PE(20-29)|pad(30-31)|attn(32-41)

typedef _Float16 hfrag __attribute__((ext_vector_type(8)));  // 8 fp16, 4 VGPRs
typedef float ffrag __attribute__((ext_vector_type(4)));     // MFMA C/D

#define MFMA_(a, b, c) __builtin_amdgcn_mfma_f32_16x16x32_f16(a, b, c, 0, 0, 0)

// Packed-fragment layouts (fp16):
//   Apk [(g*48 + kt)*64 + lane][8]   : A[row=g*16+l16][k=kt*32+quad*8+j]
//   Wpk [(cg*48 + kt)*64 + lane][8]  : W[col=cg*16+l16][k...]
//   W2pk/A2pk [(ct*5+ks)*64 + lane][8]
// Column map (col = cg*16 + l16):
//   [0,160)  P1  (cj=col,     k<1024,  sW1 rows 0..1023)
//   [160,320) P2 (cj=col-160, k<1024,  sW1 rows 1024..2047)
//   [320,480) PE (cj=col-320, k>=1024, sW1 rows 2048..2559)
//   [480,512) zero pad
//   [512,672) attn (cj=col-512, k<1024, aW1)

#define ITEMS_A   (LTOK * (KA / 8))   // 786432
#define ITEMS_W   (NCG * NKT * 64)    // 129024
#define ITEMS_W2  (K2 * (K2 / 8))     // 3200 (sW2)
#define ITEMS_A2  (K2 * (K2 / 8))     // 3200 (aW2)
#define ITEMS_TOT (ITEMS_A + ITEMS_W + ITEMS_W2 + ITEMS_A2)   // 921856 = 3601*256

// ---------------------------------------------------------------------------
// prep: fp32 -> fp16 conversion + MFMA-fragment packing (coalesced streams).
// ---------------------------------------------------------------------------
__global__ __launch_bounds__(256) void prep_kernel(
    const float* __restrict__ embeds, const float* __restrict__ states,
    const float* __restrict__ aW1, const float* __restrict__ aW2,
    const float* __restrict__ sW1, const float* __restrict__ sW2,
    _Float16* __restrict__ Apk, _Float16* __restrict__ Wpk,
    _Float16* __restrict__ W2pk, _Float16* __restrict__ A2pk)
{
    int it = blockIdx.x * 256 + threadIdx.x;
    if (it < ITEMS_A) {
        const int rem = it % (NKT * 64);
        const int g = it / (NKT * 64), kt = rem >> 6, lane = rem & 63;
        const int row = g * 16 + (lane & 15);
        const int k0 = kt * 32 + (lane >> 4) * 8;
        const float* src = (k0 < SDIM) ? (states + (size_t)row * SDIM + k0)
                                       : (embeds + (size_t)row * EDIM + (k0 - SDIM));
        const float4 v0 = *(const float4*)src;
        const float4 v1 = *(const float4*)(src + 4);
        _Float16 o[8] = {(_Float16)v0.x, (_Float16)v0.y, (_Float16)v0.z, (_Float16)v0.w,
                         (_Float16)v1.x, (_Float16)v1.y, (_Float16)v1.z, (_Float16)v1.w};
        *(uint4*)(Apk + (size_t)it * 8) = *(uint4*)o;
        return;
    }
    it -= ITEMS_A;
    if (it < ITEMS_W) {
        const int rem = it % (NKT * 64);
        const int cgi = it / (NKT * 64), kt = rem >> 6, lane = rem & 63;
        const int col = cgi * 16 + (lane & 15);
        const int k0 = kt * 32 + (lane >> 4) * 8;
        _Float16 o[8];
        for (int j = 0; j < 8; ++j) {
            const int k = k0 + j;
            float wv = 0.f;
            if (col < 160) {
                if (col < HDIM && k < SDIM) wv = sW1[(size_t)k * HDIM + col];
            } else if (col < 320) {
                const int cj = col - 160;
                if (cj < HDIM && k < SDIM) wv = sW1[(size_t)(SDIM + k) * HDIM + cj];
            } else if (col < 480) {
                const int cj = col - 320;
                if (cj < HDIM && k >= SDIM) wv = sW1[(size_t)(SDIM + k) * HDIM + cj]; // rows 2048+(k-1024)
            } else if (col >= 512) {
                const int cj = col - 512;
                if (cj < HDIM && k < SDIM) wv = aW1[(size_t)k * HDIM + cj];
            }
            o[j] = (_Float16)wv;
        }
        *(uint4*)(Wpk + ((size_t)((size_t)cgi * NKT + kt) * 64 + lane) * 8) = *(uint4*)o;
        return;
    }
    it -= ITEMS_W;
    if (it < ITEMS_W2 + ITEMS_A2) {
        const bool is_a = (it >= ITEMS_W2);
        const int li = is_a ? (it - ITEMS_W2) : it;
        const float* src = is_a ? aW2 : sW2;
        _Float16* dst = is_a ? A2pk : W2pk;
        const int tk = li >> 6, lane = li & 63;          // tk = ct*5+ks (0..49)
        const int col = (tk / 5) * 16 + (lane & 15);
        const int k0 = (tk % 5) * 32 + (lane >> 4) * 8;
        _Float16 o[8];
        for (int j = 0; j < 8; ++j) {
            const int k = k0 + j;
            float wv = (col < HDIM && k < HDIM) ? src[(size_t)k * HDIM + col] : 0.f;
            o[j] = (_Float16)wv;
        }
        *(uint4*)(dst + ((size_t)tk * 64 + lane) * 8) = *(uint4*)o;
    }
}

// ---------------------------------------------------------------------------
// k_proj: bid%9==0 -> attention-scorer block (heavy, 64 tokens, idx bid/9);
// else main projection tile (tile = bid - bid/9 - 1, BM=64 x BN=64 over 512
// cols) with K-range pruning. Latency fix (R4): explicitly-named staging
// register sets, software-pipelined depth-1 ahead -> 8-11 loads in flight
// per wave instead of the compiler's ~2 (VGPR 56 in R3 = serialized chain).
// No LDS / barriers in the main path.
// ---------------------------------------------------------------------------
__global__ __launch_bounds__(256) void k_proj(
    const _Float16* __restrict__ Apk, const _Float16* __restrict__ Wpk,
    const _Float16* __restrict__ A2pk,
    const float* __restrict__ ab1, const float* __restrict__ ab2,
    const float* __restrict__ aW3, const float* __restrict__ ab3,
    _Float16* __restrict__ P1h, _Float16* __restrict__ P2h,
    _Float16* __restrict__ PEh, float* __restrict__ attns)
{
    const int bid = blockIdx.x;
    const int tid = threadIdx.x;
    const int w = tid >> 6, lane = tid & 63;
    const int quad = lane >> 4, l16 = lane & 15;

    __shared__ __align__(16) _Float16 ah1[64 * SEG];   // attn path only (20 KB)

    if (bid % 9 == 0) {
        // ---------------- attention scorer, 64 tokens ----------------
        const int tok0 = (bid / 9) * 64;
        const int g = tok0 / 16 + w;                   // wave w: rows w*16..+15

        ffrag acc[10];
#pragma unroll
        for (int c = 0; c < 10; ++c) acc[c] = (ffrag){0.f, 0.f, 0.f, 0.f};

        const _Float16* ap = Apk + ((size_t)g * NKT) * 512 + lane * 8;
        const _Float16* wb = Wpk + lane * 8;

#define LDA_(kt) (*(const hfrag*)(ap + (size_t)(kt) * 512))
#define LOADC(BX, kt, h)                                                    \
        _Pragma("unroll")                                                   \
        for (int c_ = 0; c_ < 5; ++c_)                                      \
            BX[c_] = *(const hfrag*)(wb +                                   \
                ((size_t)(32 + (h) * 5 + c_) * NKT + (kt)) * 512);
#define MFMA5(av, BX, h)                                                    \
        _Pragma("unroll")                                                   \
        for (int c_ = 0; c_ < 5; ++c_)                                      \
            acc[(h) * 5 + c_] = MFMA_(av, BX[c_], acc[(h) * 5 + c_]);

        hfrag aA = LDA_(0), aB;
        hfrag bX[5], bY[5];
        LOADC(bX, 0, 0);
        for (int kt = 0; kt < 32; ++kt) {              // attn weights: k<1024
            LOADC(bY, kt, 1);
            if (kt + 1 < 32) aB = LDA_(kt + 1);
            MFMA5(aA, bX, 0);
            if (kt + 1 < 32) LOADC(bX, kt + 1, 0);
            MFMA5(aA, bY, 1);
            aA = aB;
        }
#undef LDA_
#undef LOADC
#undef MFMA5

        // layer1 epilogue -> LDS (relu + bias)
#pragma unroll
        for (int c = 0; c < 10; ++c) {
            const int col = c * 16 + l16;
            const float b1 = (col < HDIM) ? ab1[col] : 0.f;
#pragma unroll
            for (int r = 0; r < 4; ++r) {
                const int row = w * 16 + quad * 4 + r;
                ah1[row * SEG + col] = (_Float16)fmaxf(acc[c][r] + b1, 0.f);
            }
        }
        __syncthreads();

        // layers 2+3: wave w -> its 16 tokens
        hfrag af[5];
#pragma unroll
        for (int ks = 0; ks < 5; ++ks)
            af[ks] = *(const hfrag*)&ah1[(w * 16 + l16) * SEG + ks * 32 + quad * 8];

        float part[4] = {0.f, 0.f, 0.f, 0.f};
        for (int ct = 0; ct < 10; ++ct) {
            ffrag a2 = (ffrag){0.f, 0.f, 0.f, 0.f};
#pragma unroll
            for (int ks = 0; ks < 5; ++ks) {
                const hfrag fb = *(const hfrag*)(
                    A2pk + ((size_t)(ct * 5 + ks) * 64 + lane) * 8);
                a2 = __builtin_amdgcn_mfma_f32_16x16x32_f16(af[ks], fb, a2, 0, 0, 0);
            }
            const int col = ct * 16 + l16;
            const float s2 = (col < HDIM) ? ab2[col] : 0.f;
            const float s3 = (col < HDIM) ? aW3[col] : 0.f;
#pragma unroll
            for (int r = 0; r < 4; ++r) part[r] += fmaxf(a2[r] + s2, 0.f) * s3;
        }
#pragma unroll
        for (int off = 1; off < 16; off <<= 1) {
#pragma unroll
            for (int r = 0; r < 4; ++r) part[r] += __shfl_xor(part[r], off, 64);
        }
        if (l16 == 0) {
            const float b3 = ab3[0];
#pragma unroll
            for (int r = 0; r < 4; ++r)
                attns[tok0 + w * 16 + quad * 4 + r] = part[r] + b3;
        }
        return;
    }

    // ---------------- main projection tiles ----------------
    const int tile = bid - bid / 9 - 1;                // [0, 512)
    const int bM = tile & 63, bN = tile >> 6;          // bN in [0,8)
    const int wm = w & 1, wn = w >> 1;
    const int gbase = bM * 4 + wm * 2;
    const int cgbase = bN * 4 + wn * 2;
    if (cgbase >= 30) return;                          // dead pad col-groups
    const int kt0 = (bN >= 5) ? 32 : 0;                // PE segment: k>=1024 only
    const int kt1 = (bN >= 5) ? 48 : 32;               // P1/P2: k<1024 only

    ffrag acc[2][2];
#pragma unroll
    for (int t = 0; t < 2; ++t)
#pragma unroll
        for (int u = 0; u < 2; ++u) acc[t][u] = (ffrag){0.f, 0.f, 0.f, 0.f};

    const _Float16* a0p = Apk + ((size_t)(gbase + 0) * NKT) * 512 + lane * 8;
    const _Float16* a1p = Apk + ((size_t)(gbase + 1) * NKT) * 512 + lane * 8;
    const _Float16* b0p = Wpk + ((size_t)(cgbase + 0) * NKT) * 512 + lane * 8;
    const _Float16* b1p = Wpk + ((size_t)(cgbase + 1) * NKT) * 512 + lane * 8;

    // 2-set modulo-scheduled pipeline; all staging indices compile-time.
    hfrag Ax0[2], Ax1[2], Bx0[2], Bx1[2];
    hfrag Ay0[2], Ay1[2], By0[2], By1[2];

#define LOADB(A0_, A1_, B0_, B1_, kb)                                       \
    _Pragma("unroll")                                                       \
    for (int u_ = 0; u_ < 2; ++u_) {                                        \
        A0_[u_] = *(const hfrag*)(a0p + (size_t)((kb) + u_) * 512);         \
        A1_[u_] = *(const hfrag*)(a1p + (size_t)((kb) + u_) * 512);         \
        B0_[u_] = *(const hfrag*)(b0p + (size_t)((kb) + u_) * 512);         \
        B1_[u_] = *(const hfrag*)(b1p + (size_t)((kb) + u_) * 512);         \
    }
#define MFMAB(A0_, A1_, B0_, B1_)                                           \
    _Pragma("unroll")                                                       \
    for (int u_ = 0; u_ < 2; ++u_) {                                        \
        acc[0][0] = MFMA_(A0_[u_], B0_[u_], acc[0][0]);                     \
        acc[1][0] = MFMA_(A1_[u_], B0_[u_], acc[1][0]);                     \
        acc[0][1] = MFMA_(A0_[u_], B1_[u_], acc[0][1]);                     \
        acc[1][1] = MFMA_(A1_[u_], B1_[u_], acc[1][1]);                     \
    }

    LOADB(Ax0, Ax1, Bx0, Bx1, kt0);
    for (int kb = kt0; kb < kt1; kb += 4) {
        LOADB(Ay0, Ay1, By0, By1, kb + 2);
        MFMAB(Ax0, Ax1, Bx0, Bx1);
        if (kb + 4 < kt1) LOADB(Ax0, Ax1, Bx0, Bx1, kb + 4);
        MFMAB(Ay0, Ay1, By0, By1);
    }
#undef LOADB
#undef MFMAB

#pragma unroll
    for (int t = 0; t < 2; ++t)
#pragma unroll
        for (int u = 0; u < 2; ++u) {
            const int col = (cgbase + u) * 16 + l16;
#pragma unroll
            for (int r = 0; r < 4; ++r) {
                const int row = (gbase + t) * 16 + quad * 4 + r;
                const _Float16 hv = (_Float16)acc[t][u][r];
                if (col < 160)      P1h[(size_t)row * SEG + col] = hv;
                else if (col < 320) P2h[(size_t)row * SEG + (col - 160)] = hv;
                else if (col < 480) PEh[(size_t)row * SEG + (col - 320)] = hv;
            }
        }
}

// ---------------------------------------------------------------------------
// span (n-paired, interleaved): pairI = bid % 5, mChunk = bid / 5. Handles
// n0=2*pairI+1 and n1=n0+1 for 32 m-values, sharing P1/PE loads. The 41
// unique PE rows (clamped) are staged once in LDS. PE loop fully unrolled
// to MAXN with zero weights past n (exact no-op fmaf).
// ---------------------------------------------------------------------------
__global__ __launch_bounds__(256) void span_kernel(
    const float* __restrict__ attns, const _Float16* __restrict__ P1h,
    const _Float16* __restrict__ P2h, const _Float16* __restrict__ PEh,
    const float* __restrict__ sb1, const _Float16* __restrict__ W2pk,
    const float* __restrict__ sb2, const float* __restrict__ sW3,
    const float* __restrict__ sb3, float* __restrict__ out)
{
    const int pairI = blockIdx.x % 5;         // 0..4 (interleaved heavy/light)
    const int mChunk = blockIdx.x / 5;        // 0..127
    const int n0 = 2 * pairI + 1, n1 = n0 + 1;
    const int Mn0 = LTOK - n0 + 1, Mn1 = Mn0 - 1;
    const int m0 = mChunk * 32;
    const int offn0 = (n0 - 1) * LTOK - ((n0 - 1) * (n0 - 2)) / 2;
    const int offn1 = offn0 + Mn0;

    const int tid = threadIdx.x;
    const int w = tid >> 6, lane = tid & 63, quad = lane >> 4, l16 = lane & 15;

    __shared__ __align__(16) _Float16 h1h[2][32 * K2];
    __shared__ __align__(16) _Float16 PEs[41 * SEG];   // staged PE rows (13 KB)
    __shared__ float wgt[2][32][MAXN];

    // stage PE rows m0..m0+40 (row-clamped) into LDS
    for (int t = tid; t < 41 * (SEG / 8); t += 256) {
        const int rr = t / (SEG / 8), cc = t % (SEG / 8);
        const int srcRow = min(m0 + rr, LTOK - 1);
        *(uint4*)&PEs[rr * SEG + cc * 8] =
            *(const uint4*)(PEh + (size_t)srcRow * SEG + cc * 8);
    }

    if (tid < 64) {
        const int q = tid >> 5, r = tid & 31;
        const int n = q ? n1 : n0;
        const int Mn = q ? Mn1 : Mn0;
        const int m = m0 + r;
        if (m < Mn) {
            float av[MAXN];
#pragma unroll
            for (int j = 0; j < MAXN; ++j)
                av[j] = attns[min(m + j, LTOK - 1)];   // parallel clamped loads
            float mx = -1e30f;
            for (int j = 0; j < n; ++j) mx = fmaxf(mx, av[j]);
            float tp[MAXN]; float s = 0.f;
            for (int j = 0; j < n; ++j) { tp[j] = expf(av[j] - mx); s += tp[j]; }
            const float inv = 1.f / s;
            for (int j = 0; j < MAXN; ++j) wgt[q][r][j] = (j < n) ? tp[j] * inv : 0.f;
        } else {
            for (int j = 0; j < MAXN; ++j) wgt[q][r][j] = 0.f;
        }
    }
    __syncthreads();

    // phase 1: 32 rows x 20 col-chunks (8 cols), BOTH n per item; full unroll
    for (int item = tid; item < 32 * (K2 / 8); item += 256) {
        const int r = item / (K2 / 8), cc = item % (K2 / 8);
        const int c0 = cc * 8;
        const int mm = m0 + r;                       // < 4096 always
        const hfrag p1  = *(const hfrag*)(P1h + (size_t)mm * SEG + c0);
        const hfrag p2a = *(const hfrag*)(P2h + (size_t)min(mm + n0 - 1, LTOK - 1) * SEG + c0);
        const hfrag p2b = *(const hfrag*)(P2h + (size_t)min(mm + n0, LTOK - 1) * SEG + c0);
        float b1v[8];
#pragma unroll
        for (int e = 0; e < 8; ++e)
            b1v[e] = (c0 + e < HDIM) ? sb1[c0 + e] : 0.f;
        float a0[8], a1[8];
#pragma unroll
        for (int e = 0; e < 8; ++e) {
            a0[e] = (float)p1[e] + (float)p2a[e] + b1v[e];
            a1[e] = (float)p1[e] + (float)p2b[e] + b1v[e];
        }
#pragma unroll
        for (int j = 0; j < MAXN; ++j) {             // weights 0 past n -> exact no-op
            const hfrag pe = *(const hfrag*)&PEs[(r + j) * SEG + c0];
            const float w0j = wgt[0][r][j];
            const float w1j = wgt[1][r][j];
#pragma unroll
            for (int e = 0; e < 8; ++e) {
                const float pv = (float)pe[e];
                a0[e] = fmaf(w0j, pv, a0[e]);
                a1[e] = fmaf(w1j, pv, a1[e]);
            }
        }
        _Float16 o0[8], o1[8];
#pragma unroll
        for (int e = 0; e < 8; ++e) {
            const bool live = (c0 + e < HDIM);
            o0[e] = live ? (_Float16)fmaxf(a0[e], 0.f) : (_Float16)0.f;
            o1[e] = live ? (_Float16)fmaxf(a1[e], 0.f) : (_Float16)0.f;
        }
        *(uint4*)&h1h[0][r * K2 + c0] = *(uint4*)o0;
        *(uint4*)&h1h[1][r * K2 + c0] = *(uint4*)o1;
    }
    __syncthreads();

    // phase 2: wave w -> side q = w>>1, row-group rg = w&1 (16 rows)
    const int q = w >> 1, rg = w & 1;
    const int Mq = q ? Mn1 : Mn0;
    const int offq = q ? offn1 : offn0;

    hfrag af[5];
#pragma unroll
    for (int ks = 0; ks < 5; ++ks)
        af[ks] = *(const hfrag*)&h1h[q][(rg * 16 + l16) * K2 + ks * 32 + quad * 8];

    float part[4] = {0.f, 0.f, 0.f, 0.f};
    for (int ct = 0; ct < 10; ++ct) {
        ffrag acc = (ffrag){0.f, 0.f, 0.f, 0.f};
#pragma unroll
        for (int ks = 0; ks < 5; ++ks) {
            const hfrag fb = *(const hfrag*)(
                W2pk + ((size_t)(ct * 5 + ks) * 64 + lane) * 8);
            acc = __builtin_amdgcn_mfma_f32_16x16x32_f16(af[ks], fb, acc, 0, 0, 0);
        }
        const int col = ct * 16 + l16;
        const float s2 = (col < HDIM) ? sb2[col] : 0.f;
        const float s3 = (col < HDIM) ? sW3[col] : 0.f;
#pragma unroll
        for (int r = 0; r < 4; ++r) part[r] += fmaxf(acc[r] + s2, 0.f) * s3;
    }

#pragma unroll
    for (int off = 1; off < 16; off <<= 1) {
#pragma unroll
        for (int r = 0; r < 4; ++r) part[r] += __shfl_xor(part[r], off, 64);
    }
    if (l16 == 0) {
        const float b3 = sb3[0];
#pragma unroll
        for (int r = 0; r < 4; ++r) {
            const int lr = rg * 16 + quad * 4 + r;   // 0..31
            if (m0 + lr < Mq) out[offq + m0 + lr] = part[r] + b3;
        }
    }
}

// ---------------------------------------------------------------------------
extern "C" void kernel_launch(void* const* d_in, const int* in_sizes, int n_in,
                              void* d_out, int out_size, void* d_ws, size_t ws_size,
                              hipStream_t stream) {
    const float* embeds = (const float*)d_in[0];
    const float* states = (const float*)d_in[1];
    const float* aW1 = (const float*)d_in[2];
    const float* ab1 = (const float*)d_in[3];
    const float* aW2 = (const float*)d_in[4];
    const float* ab2 = (const float*)d_in[5];
    const float* aW3 = (const float*)d_in[6];
    const float* ab3 = (const float*)d_in[7];
    const float* sW1 = (const float*)d_in[8];
    const float* sb1 = (const float*)d_in[9];
    const float* sW2 = (const float*)d_in[10];
    const float* sb2 = (const float*)d_in[11];
    const float* sW3 = (const float*)d_in[12];
    const float* sb3 = (const float*)d_in[13];
    float* out = (float*)d_out;

    // ws: fp32 attns | fp16 P1h | P2h | PEh (SEG rows) | Apk | Wpk | W2pk | A2pk
    float* attns = (float*)d_ws;
    _Float16* P1h  = (_Float16*)(attns + LTOK);
    _Float16* P2h  = P1h + (size_t)LTOK * SEG;
    _Float16* PEh  = P2h + (size_t)LTOK * SEG;
    _Float16* Apk  = PEh + (size_t)LTOK * SEG;
    _Float16* Wpk  = Apk + (size_t)ITEMS_A * 8;
    _Float16* W2pk = Wpk + (size_t)ITEMS_W * 8;
    _Float16* A2pk = W2pk + (size_t)ITEMS_W2 * 8;
    // total ~19 MB

    prep_kernel<<<ITEMS_TOT / 256, 256, 0, stream>>>(
        embeds, states, aW1, aW2, sW1, sW2, Apk, Wpk, W2pk, A2pk);
    k_proj<<<576, 256, 0, stream>>>(
        Apk, Wpk, A2pk, ab1, ab2, aW3, ab3, P1h, P2h, PEh, attns);
    span_kernel<<<640, 256, 0, stream>>>(
        attns, P1h, P2h, PEh, sb1, W2pk, sb2, sW3, sb3, out);
}

// Round 5
// 143.732 us; speedup vs baseline: 1.0880x; 1.0062x over previous
//
#include <hip/hip_runtime.h>
#include <math.h>

#define LTOK 4096
#define EDIM 512
#define SDIM 1024
#define HDIM 150
#define SEG 160            // padded segment width (cols) and P-row stride
#define MAXN 10
#define TOTAL_ROWS 40915   // sum_{n=1..10} (L - n + 1)
#define KA 1536            // padded K: 1024 states + 512 embeds
#define NKT 48             // k-tiles of 32
#define K2 160             // padded K and N for 150x150 layers
#define NCG 42             // packed-W col groups: P1(0-9)|P2(10-19)|PE(20-29)|pad(30-31)|attn(32-41)

typedef _Float16 hfrag __attribute__((ext_vector_type(8)));  // 8 fp16, 4 VGPRs
typedef float ffrag __attribute__((ext_vector_type(4)));     // MFMA C/D

#define MFMA_(a, b, c) __builtin_amdgcn_mfma_f32_16x16x32_f16(a, b, c, 0, 0, 0)

// Packed-fragment layouts (fp16):
//   Apk [(g*48 + kt)*64 + lane][8]   : A[row=g*16+l16][k=kt*32+quad*8+j]
//   Wpk [(cg*48 + kt)*64 + lane][8]  : W[col=cg*16+l16][k...]
//   W2pk/A2pk [(ct*5+ks)*64 + lane][8]
// Column map (col = cg*16 + l16):
//   [0,160)  P1  (cj=col,     k<1024,  sW1 rows 0..1023)
//   [160,320) P2 (cj=col-160, k<1024,  sW1 rows 1024..2047)
//   [320,480) PE (cj=col-320, k>=1024, sW1 rows 2048..2559)
//   [480,512) zero pad
//   [512,672) attn (cj=col-512, k<1024, aW1)

#define ITEMS_A   (LTOK * (KA / 8))   // 786432
#define ITEMS_W   (NCG * NKT * 64)    // 129024
#define ITEMS_W2  (K2 * (K2 / 8))     // 3200 (sW2)
#define ITEMS_A2  (K2 * (K2 / 8))     // 3200 (aW2)
#define ITEMS_TOT (ITEMS_A + ITEMS_W + ITEMS_W2 + ITEMS_A2)   // 921856 = 3601*256

// ---------------------------------------------------------------------------
// prep: fp32 -> fp16 conversion + MFMA-fragment packing (coalesced streams).
// ---------------------------------------------------------------------------
__global__ __launch_bounds__(256) void prep_kernel(
    const float* __restrict__ embeds, const float* __restrict__ states,
    const float* __restrict__ aW1, const float* __restrict__ aW2,
    const float* __restrict__ sW1, const float* __restrict__ sW2,
    _Float16* __restrict__ Apk, _Float16* __restrict__ Wpk,
    _Float16* __restrict__ W2pk, _Float16* __restrict__ A2pk)
{
    int it = blockIdx.x * 256 + threadIdx.x;
    if (it < ITEMS_A) {
        const int rem = it % (NKT * 64);
        const int g = it / (NKT * 64), kt = rem >> 6, lane = rem & 63;
        const int row = g * 16 + (lane & 15);
        const int k0 = kt * 32 + (lane >> 4) * 8;
        const float* src = (k0 < SDIM) ? (states + (size_t)row * SDIM + k0)
                                       : (embeds + (size_t)row * EDIM + (k0 - SDIM));
        const float4 v0 = *(const float4*)src;
        const float4 v1 = *(const float4*)(src + 4);
        _Float16 o[8] = {(_Float16)v0.x, (_Float16)v0.y, (_Float16)v0.z, (_Float16)v0.w,
                         (_Float16)v1.x, (_Float16)v1.y, (_Float16)v1.z, (_Float16)v1.w};
        *(uint4*)(Apk + (size_t)it * 8) = *(uint4*)o;
        return;
    }
    it -= ITEMS_A;
    if (it < ITEMS_W) {
        const int rem = it % (NKT * 64);
        const int cgi = it / (NKT * 64), kt = rem >> 6, lane = rem & 63;
        const int col = cgi * 16 + (lane & 15);
        const int k0 = kt * 32 + (lane >> 4) * 8;
        _Float16 o[8];
        for (int j = 0; j < 8; ++j) {
            const int k = k0 + j;
            float wv = 0.f;
            if (col < 160) {
                if (col < HDIM && k < SDIM) wv = sW1[(size_t)k * HDIM + col];
            } else if (col < 320) {
                const int cj = col - 160;
                if (cj < HDIM && k < SDIM) wv = sW1[(size_t)(SDIM + k) * HDIM + cj];
            } else if (col < 480) {
                const int cj = col - 320;
                if (cj < HDIM && k >= SDIM) wv = sW1[(size_t)(SDIM + k) * HDIM + cj]; // rows 2048+(k-1024)
            } else if (col >= 512) {
                const int cj = col - 512;
                if (cj < HDIM && k < SDIM) wv = aW1[(size_t)k * HDIM + cj];
            }
            o[j] = (_Float16)wv;
        }
        *(uint4*)(Wpk + ((size_t)((size_t)cgi * NKT + kt) * 64 + lane) * 8) = *(uint4*)o;
        return;
    }
    it -= ITEMS_W;
    if (it < ITEMS_W2 + ITEMS_A2) {
        const bool is_a = (it >= ITEMS_W2);
        const int li = is_a ? (it - ITEMS_W2) : it;
        const float* src = is_a ? aW2 : sW2;
        _Float16* dst = is_a ? A2pk : W2pk;
        const int tk = li >> 6, lane = li & 63;          // tk = ct*5+ks (0..49)
        const int col = (tk / 5) * 16 + (lane & 15);
        const int k0 = (tk % 5) * 32 + (lane >> 4) * 8;
        _Float16 o[8];
        for (int j = 0; j < 8; ++j) {
            const int k = k0 + j;
            float wv = (col < HDIM && k < HDIM) ? src[(size_t)k * HDIM + col] : 0.f;
            o[j] = (_Float16)wv;
        }
        *(uint4*)(dst + ((size_t)tk * 64 + lane) * 8) = *(uint4*)o;
    }
}

// ---------------------------------------------------------------------------
// k_proj (R5): grid = 64 attn blocks (bid<64, 64 tokens each, unchanged code)
// + 128 main blocks, all co-resident (single round). Main wave tile enlarged
// to 64x64 output (acc[4][4], 16 MFMA per kt, 8 KB loads per kt) = 0.5
// KB/MFMA -> 2x L2/L3 traffic cut vs 32x32, no barriers. Two named register
// sets, compile-time indices, same kt order -> bit-identical.
// ---------------------------------------------------------------------------
__global__ __launch_bounds__(256) void k_proj(
    const _Float16* __restrict__ Apk, const _Float16* __restrict__ Wpk,
    const _Float16* __restrict__ A2pk,
    const float* __restrict__ ab1, const float* __restrict__ ab2,
    const float* __restrict__ aW3, const float* __restrict__ ab3,
    _Float16* __restrict__ P1h, _Float16* __restrict__ P2h,
    _Float16* __restrict__ PEh, float* __restrict__ attns)
{
    const int bid = blockIdx.x;
    const int tid = threadIdx.x;
    const int w = tid >> 6, lane = tid & 63;
    const int quad = lane >> 4, l16 = lane & 15;

    __shared__ __align__(16) _Float16 ah1[64 * SEG];   // attn path only (20 KB)

    if (bid < 64) {
        // ---------------- attention scorer, 64 tokens ----------------
        const int tok0 = bid * 64;
        const int g = tok0 / 16 + w;                   // wave w: rows w*16..+15

        ffrag acc[10];
#pragma unroll
        for (int c = 0; c < 10; ++c) acc[c] = (ffrag){0.f, 0.f, 0.f, 0.f};

        const _Float16* ap = Apk + ((size_t)g * NKT) * 512 + lane * 8;
        const _Float16* wb = Wpk + lane * 8;

#define LDA_(kt) (*(const hfrag*)(ap + (size_t)(kt) * 512))
#define LOADC(BX, kt, h)                                                    \
        _Pragma("unroll")                                                   \
        for (int c_ = 0; c_ < 5; ++c_)                                      \
            BX[c_] = *(const hfrag*)(wb +                                   \
                ((size_t)(32 + (h) * 5 + c_) * NKT + (kt)) * 512);
#define MFMA5(av, BX, h)                                                    \
        _Pragma("unroll")                                                   \
        for (int c_ = 0; c_ < 5; ++c_)                                      \
            acc[(h) * 5 + c_] = MFMA_(av, BX[c_], acc[(h) * 5 + c_]);

        hfrag aA = LDA_(0), aB;
        hfrag bX[5], bY[5];
        LOADC(bX, 0, 0);
        for (int kt = 0; kt < 32; ++kt) {              // attn weights: k<1024
            LOADC(bY, kt, 1);
            if (kt + 1 < 32) aB = LDA_(kt + 1);
            MFMA5(aA, bX, 0);
            if (kt + 1 < 32) LOADC(bX, kt + 1, 0);
            MFMA5(aA, bY, 1);
            aA = aB;
        }
#undef LDA_
#undef LOADC
#undef MFMA5

        // layer1 epilogue -> LDS (relu + bias)
#pragma unroll
        for (int c = 0; c < 10; ++c) {
            const int col = c * 16 + l16;
            const float b1 = (col < HDIM) ? ab1[col] : 0.f;
#pragma unroll
            for (int r = 0; r < 4; ++r) {
                const int row = w * 16 + quad * 4 + r;
                ah1[row * SEG + col] = (_Float16)fmaxf(acc[c][r] + b1, 0.f);
            }
        }
        __syncthreads();

        // layers 2+3: wave w -> its 16 tokens
        hfrag af[5];
#pragma unroll
        for (int ks = 0; ks < 5; ++ks)
            af[ks] = *(const hfrag*)&ah1[(w * 16 + l16) * SEG + ks * 32 + quad * 8];

        float part[4] = {0.f, 0.f, 0.f, 0.f};
        for (int ct = 0; ct < 10; ++ct) {
            ffrag a2 = (ffrag){0.f, 0.f, 0.f, 0.f};
#pragma unroll
            for (int ks = 0; ks < 5; ++ks) {
                const hfrag fb = *(const hfrag*)(
                    A2pk + ((size_t)(ct * 5 + ks) * 64 + lane) * 8);
                a2 = __builtin_amdgcn_mfma_f32_16x16x32_f16(af[ks], fb, a2, 0, 0, 0);
            }
            const int col = ct * 16 + l16;
            const float s2 = (col < HDIM) ? ab2[col] : 0.f;
            const float s3 = (col < HDIM) ? aW3[col] : 0.f;
#pragma unroll
            for (int r = 0; r < 4; ++r) part[r] += fmaxf(a2[r] + s2, 0.f) * s3;
        }
#pragma unroll
        for (int off = 1; off < 16; off <<= 1) {
#pragma unroll
            for (int r = 0; r < 4; ++r) part[r] += __shfl_xor(part[r], off, 64);
        }
        if (l16 == 0) {
            const float b3 = ab3[0];
#pragma unroll
            for (int r = 0; r < 4; ++r)
                attns[tok0 + w * 16 + quad * 4 + r] = part[r] + b3;
        }
        return;
    }

    // ---------------- main projection tiles: 64x64 per wave ----------------
    const int mb = bid - 64;                           // [0, 128)
    const int bM = mb & 63;                            // M-tile (64 rows)
    const int bH = mb >> 6;                            // col half: 0 or 1
    const int gbase = bM * 4;                          // 4 row-groups
    const int cgbase = bH * 16 + w * 4;                // 4 col-groups per wave
    const int kt0 = (cgbase >= 20) ? 32 : 0;           // PE segment: k>=1024
    const int kt1 = (cgbase >= 20) ? 48 : 32;          // P1/P2: k<1024

    ffrag acc[4][4];
#pragma unroll
    for (int t = 0; t < 4; ++t)
#pragma unroll
        for (int u = 0; u < 4; ++u) acc[t][u] = (ffrag){0.f, 0.f, 0.f, 0.f};

    const _Float16* aB = Apk + ((size_t)gbase * NKT) * 512 + lane * 8;
    const _Float16* bB = Wpk + ((size_t)cgbase * NKT) * 512 + lane * 8;

    hfrag AX[4], BX[4], AY[4], BY[4];

#define LDSET(AS_, BS_, kt)                                                 \
    _Pragma("unroll")                                                       \
    for (int g_ = 0; g_ < 4; ++g_) {                                        \
        AS_[g_] = *(const hfrag*)(aB + ((size_t)g_ * NKT + (kt)) * 512);    \
        BS_[g_] = *(const hfrag*)(bB + ((size_t)g_ * NKT + (kt)) * 512);    \
    }
#define MFMASET(AS_, BS_)                                                   \
    _Pragma("unroll")                                                       \
    for (int t_ = 0; t_ < 4; ++t_)                                          \
        _Pragma("unroll")                                                   \
        for (int u_ = 0; u_ < 4; ++u_)                                      \
            acc[t_][u_] = MFMA_(AS_[t_], BS_[u_], acc[t_][u_]);

    LDSET(AX, BX, kt0);
    for (int kt = kt0; kt < kt1; kt += 2) {            // kt count 32 or 16 (even)
        LDSET(AY, BY, kt + 1);
        MFMASET(AX, BX);
        if (kt + 2 < kt1) LDSET(AX, BX, kt + 2);
        MFMASET(AY, BY);
    }
#undef LDSET
#undef MFMASET

#pragma unroll
    for (int t = 0; t < 4; ++t)
#pragma unroll
        for (int u = 0; u < 4; ++u) {
            const int col = (cgbase + u) * 16 + l16;
#pragma unroll
            for (int r = 0; r < 4; ++r) {
                const int row = (gbase + t) * 16 + quad * 4 + r;
                const _Float16 hv = (_Float16)acc[t][u][r];
                if (col < 160)      P1h[(size_t)row * SEG + col] = hv;
                else if (col < 320) P2h[(size_t)row * SEG + (col - 160)] = hv;
                else if (col < 480) PEh[(size_t)row * SEG + (col - 320)] = hv;
            }
        }
}

// ---------------------------------------------------------------------------
// span (n-paired, interleaved): pairI = bid % 5, mChunk = bid / 5. Handles
// n0=2*pairI+1 and n1=n0+1 for 32 m-values, sharing P1/PE loads. The 41
// unique PE rows (clamped) are staged once in LDS. PE loop fully unrolled
// to MAXN with zero weights past n (exact no-op fmaf).
// ---------------------------------------------------------------------------
__global__ __launch_bounds__(256) void span_kernel(
    const float* __restrict__ attns, const _Float16* __restrict__ P1h,
    const _Float16* __restrict__ P2h, const _Float16* __restrict__ PEh,
    const float* __restrict__ sb1, const _Float16* __restrict__ W2pk,
    const float* __restrict__ sb2, const float* __restrict__ sW3,
    const float* __restrict__ sb3, float* __restrict__ out)
{
    const int pairI = blockIdx.x % 5;         // 0..4 (interleaved heavy/light)
    const int mChunk = blockIdx.x / 5;        // 0..127
    const int n0 = 2 * pairI + 1, n1 = n0 + 1;
    const int Mn0 = LTOK - n0 + 1, Mn1 = Mn0 - 1;
    const int m0 = mChunk * 32;
    const int offn0 = (n0 - 1) * LTOK - ((n0 - 1) * (n0 - 2)) / 2;
    const int offn1 = offn0 + Mn0;

    const int tid = threadIdx.x;
    const int w = tid >> 6, lane = tid & 63, quad = lane >> 4, l16 = lane & 15;

    __shared__ __align__(16) _Float16 h1h[2][32 * K2];
    __shared__ __align__(16) _Float16 PEs[41 * SEG];   // staged PE rows (13 KB)
    __shared__ float wgt[2][32][MAXN];

    // stage PE rows m0..m0+40 (row-clamped) into LDS
    for (int t = tid; t < 41 * (SEG / 8); t += 256) {
        const int rr = t / (SEG / 8), cc = t % (SEG / 8);
        const int srcRow = min(m0 + rr, LTOK - 1);
        *(uint4*)&PEs[rr * SEG + cc * 8] =
            *(const uint4*)(PEh + (size_t)srcRow * SEG + cc * 8);
    }

    if (tid < 64) {
        const int q = tid >> 5, r = tid & 31;
        const int n = q ? n1 : n0;
        const int Mn = q ? Mn1 : Mn0;
        const int m = m0 + r;
        if (m < Mn) {
            float av[MAXN];
#pragma unroll
            for (int j = 0; j < MAXN; ++j)
                av[j] = attns[min(m + j, LTOK - 1)];   // parallel clamped loads
            float mx = -1e30f;
            for (int j = 0; j < n; ++j) mx = fmaxf(mx, av[j]);
            float tp[MAXN]; float s = 0.f;
            for (int j = 0; j < n; ++j) { tp[j] = expf(av[j] - mx); s += tp[j]; }
            const float inv = 1.f / s;
            for (int j = 0; j < MAXN; ++j) wgt[q][r][j] = (j < n) ? tp[j] * inv : 0.f;
        } else {
            for (int j = 0; j < MAXN; ++j) wgt[q][r][j] = 0.f;
        }
    }
    __syncthreads();

    // phase 1: 32 rows x 20 col-chunks (8 cols), BOTH n per item; full unroll
    for (int item = tid; item < 32 * (K2 / 8); item += 256) {
        const int r = item / (K2 / 8), cc = item % (K2 / 8);
        const int c0 = cc * 8;
        const int mm = m0 + r;                       // < 4096 always
        const hfrag p1  = *(const hfrag*)(P1h + (size_t)mm * SEG + c0);
        const hfrag p2a = *(const hfrag*)(P2h + (size_t)min(mm + n0 - 1, LTOK - 1) * SEG + c0);
        const hfrag p2b = *(const hfrag*)(P2h + (size_t)min(mm + n0, LTOK - 1) * SEG + c0);
        float b1v[8];
#pragma unroll
        for (int e = 0; e < 8; ++e)
            b1v[e] = (c0 + e < HDIM) ? sb1[c0 + e] : 0.f;
        float a0[8], a1[8];
#pragma unroll
        for (int e = 0; e < 8; ++e) {
            a0[e] = (float)p1[e] + (float)p2a[e] + b1v[e];
            a1[e] = (float)p1[e] + (float)p2b[e] + b1v[e];
        }
#pragma unroll
        for (int j = 0; j < MAXN; ++j) {             // weights 0 past n -> exact no-op
            const hfrag pe = *(const hfrag*)&PEs[(r + j) * SEG + c0];
            const float w0j = wgt[0][r][j];
            const float w1j = wgt[1][r][j];
#pragma unroll
            for (int e = 0; e < 8; ++e) {
                const float pv = (float)pe[e];
                a0[e] = fmaf(w0j, pv, a0[e]);
                a1[e] = fmaf(w1j, pv, a1[e]);
            }
        }
        _Float16 o0[8], o1[8];
#pragma unroll
        for (int e = 0; e < 8; ++e) {
            const bool live = (c0 + e < HDIM);
            o0[e] = live ? (_Float16)fmaxf(a0[e], 0.f) : (_Float16)0.f;
            o1[e] = live ? (_Float16)fmaxf(a1[e], 0.f) : (_Float16)0.f;
        }
        *(uint4*)&h1h[0][r * K2 + c0] = *(uint4*)o0;
        *(uint4*)&h1h[1][r * K2 + c0] = *(uint4*)o1;
    }
    __syncthreads();

    // phase 2: wave w -> side q = w>>1, row-group rg = w&1 (16 rows)
    const int q = w >> 1, rg = w & 1;
    const int Mq = q ? Mn1 : Mn0;
    const int offq = q ? offn1 : offn0;

    hfrag af[5];
#pragma unroll
    for (int ks = 0; ks < 5; ++ks)
        af[ks] = *(const hfrag*)&h1h[q][(rg * 16 + l16) * K2 + ks * 32 + quad * 8];

    float part[4] = {0.f, 0.f, 0.f, 0.f};
    for (int ct = 0; ct < 10; ++ct) {
        ffrag acc = (ffrag){0.f, 0.f, 0.f, 0.f};
#pragma unroll
        for (int ks = 0; ks < 5; ++ks) {
            const hfrag fb = *(const hfrag*)(
                W2pk + ((size_t)(ct * 5 + ks) * 64 + lane) * 8);
            acc = __builtin_amdgcn_mfma_f32_16x16x32_f16(af[ks], fb, acc, 0, 0, 0);
        }
        const int col = ct * 16 + l16;
        const float s2 = (col < HDIM) ? sb2[col] : 0.f;
        const float s3 = (col < HDIM) ? sW3[col] : 0.f;
#pragma unroll
        for (int r = 0; r < 4; ++r) part[r] += fmaxf(acc[r] + s2, 0.f) * s3;
    }

#pragma unroll
    for (int off = 1; off < 16; off <<= 1) {
#pragma unroll
        for (int r = 0; r < 4; ++r) part[r] += __shfl_xor(part[r], off, 64);
    }
    if (l16 == 0) {
        const float b3 = sb3[0];
#pragma unroll
        for (int r = 0; r < 4; ++r) {
            const int lr = rg * 16 + quad * 4 + r;   // 0..31
            if (m0 + lr < Mq) out[offq + m0 + lr] = part[r] + b3;
        }
    }
}

// ---------------------------------------------------------------------------
extern "C" void kernel_launch(void* const* d_in, const int* in_sizes, int n_in,
                              void* d_out, int out_size, void* d_ws, size_t ws_size,
                              hipStream_t stream) {
    const float* embeds = (const float*)d_in[0];
    const float* states = (const float*)d_in[1];
    const float* aW1 = (const float*)d_in[2];
    const float* ab1 = (const float*)d_in[3];
    const float* aW2 = (const float*)d_in[4];
    const float* ab2 = (const float*)d_in[5];
    const float* aW3 = (const float*)d_in[6];
    const float* ab3 = (const float*)d_in[7];
    const float* sW1 = (const float*)d_in[8];
    const float* sb1 = (const float*)d_in[9];
    const float* sW2 = (const float*)d_in[10];
    const float* sb2 = (const float*)d_in[11];
    const float* sW3 = (const float*)d_in[12];
    const float* sb3 = (const float*)d_in[13];
    float* out = (float*)d_out;

    // ws: fp32 attns | fp16 P1h | P2h | PEh (SEG rows) | Apk | Wpk | W2pk | A2pk
    float* attns = (float*)d_ws;
    _Float16* P1h  = (_Float16*)(attns + LTOK);
    _Float16* P2h  = P1h + (size_t)LTOK * SEG;
    _Float16* PEh  = P2h + (size_t)LTOK * SEG;
    _Float16* Apk  = PEh + (size_t)LTOK * SEG;
    _Float16* Wpk  = Apk + (size_t)ITEMS_A * 8;
    _Float16* W2pk = Wpk + (size_t)ITEMS_W * 8;
    _Float16* A2pk = W2pk + (size_t)ITEMS_W2 * 8;
    // total ~19 MB

    prep_kernel<<<ITEMS_TOT / 256, 256, 0, stream>>>(
        embeds, states, aW1, aW2, sW1, sW2, Apk, Wpk, W2pk, A2pk);
    k_proj<<<192, 256, 0, stream>>>(
        Apk, Wpk, A2pk, ab1, ab2, aW3, ab3, P1h, P2h, PEh, attns);
    span_kernel<<<640, 256, 0, stream>>>(
        attns, P1h, P2h, PEh, sb1, W2pk, sb2, sW3, sb3, out);
}